// Round 7
// baseline (465.233 us; speedup 1.0000x reference)
//
#include <hip/hip_runtime.h>

typedef float f4 __attribute__((ext_vector_type(4)));

#define C_ROWS 32768
#define L_COLS 512
#define N_TOT  (C_ROWS * (size_t)L_COLS)

#define NB_ROW 8192                // row blocks: 4 waves, 1 row per wave
#define NB_ST  32                  // dedicated stats blocks (tiny)
#define GRID   (NB_ROW + NB_ST)

// ws layout (bytes):
//   [0, 64K)           : NB_ROW float2 — per-row-block partials (misc, sse)
//   [64K, 64K+2560)    : NB_ST * 10 doubles — per-stats-block partials
//   [68096, 68100)     : unsigned ticket counter (memset to 0 each launch)
#define STATS_OFF 65536
#define CTR_OFF   68096

__device__ __forceinline__ float frelu(float x) { return x > 0.f ? x : 0.f; }

__device__ __forceinline__ f4 ntload(const float* p) {
    return __builtin_nontemporal_load((const f4*)p);
}

__device__ __forceinline__ bool mask_at(const void* p, int i, int flag) {
    if (flag == 1) return ((const int*)p)[i] != 0;
    if (flag == 2) return ((const float*)p)[i] != 0.f;
    return ((const unsigned char*)p)[i] != 0;
}

// Per-wave mask-dtype detect from first 512 words (2 KB) of mask_nolightresp.
__device__ __forceinline__ int detect_flag(const void* m) {
    const int lane = threadIdx.x & 63;
    const uint4* p = (const uint4*)m;
    const uint4 a = p[lane * 2], b = p[lane * 2 + 1];
    unsigned w[8] = {a.x, a.y, a.z, a.w, b.x, b.y, b.z, b.w};
    int anyMid = 0, anyF = 0;
#pragma unroll
    for (int k = 0; k < 8; ++k) {
        if (w[k] & ~1u) anyMid = 1;
        if (w[k] == 0x3f800000u) anyF = 1;
    }
    const bool hasF   = __ballot(anyF) != 0ull;
    const bool hasMid = __ballot(anyMid) != 0ull;
    return hasF ? 2 : (hasMid ? 0 : 1);
}

__device__ double corrterm(double n, double Sx, double Sxx, double Sy, double Syy,
                           double Sxy, double target) {
    const double mx = Sx / n, my = Sy / n;
    const double cov = Sxy - n * mx * my;
    const double vx  = Sxx - n * mx * mx;
    const double vy  = Syy - n * my * my;
    double cost = cov / (sqrt(vx) * sqrt(vy));
    if (isnan(cost)) cost = 0.0;
    const double cmin = cost < target ? cost : target;
    return target - cmin;
}

// ----------------------------------------------------------------- fused ----
__global__ __launch_bounds__(256) void fused_kernel(const float* __restrict__ An,
                                                    const float* __restrict__ Ac,
                                                    const float* __restrict__ Aj,
                                                    const float* __restrict__ Ap,
                                                    const float* __restrict__ Ar,
                                                    const float* __restrict__ V,
                                                    const float* __restrict__ J,
                                                    const float* __restrict__ R,
                                                    const void* __restrict__ mNL,
                                                    const void* __restrict__ mFp,
                                                    const void* __restrict__ mFj,
                                                    const float* __restrict__ dHaV,
                                                    const float* __restrict__ dHaJ,
                                                    const float* __restrict__ dHaT,
                                                    const float* __restrict__ ToV,
                                                    const float* __restrict__ ToJ,
                                                    const float* __restrict__ ToT,
                                                    const float* __restrict__ gm,
                                                    void* ws, float* out) {
    const int lane = threadIdx.x & 63;
    const int wv   = threadIdx.x >> 6;
    const int bid  = blockIdx.x;
    float2* part = (float2*)ws;
    double* stats = (double*)((char*)ws + STATS_OFF);

    if (bid < NB_ROW) {
        // ---------------- row logic: 1 row per wave, all 5 arrays ------------
        const int r = bid * 4 + wv;
        const size_t base = (size_t)r * L_COLS;
        const int c0 = lane * 4;

        const f4 an0 = ntload(An + base + c0);
        const f4 an1 = ntload(An + base + 256 + c0);
        const f4 ar0 = ntload(Ar + base + c0);
        const f4 ar1 = ntload(Ar + base + 256 + c0);
        const f4 ap0 = ntload(Ap + base + c0);
        const f4 ap1 = ntload(Ap + base + 256 + c0);
        const f4 ac0 = ntload(Ac + base + c0);
        const f4 ac1 = ntload(Ac + base + 256 + c0);
        const f4 aj0 = ntload(Aj + base + c0);
        const f4 aj1 = ntload(Aj + base + 256 + c0);

        const int flag = detect_flag(mNL);     // overlaps with big loads
        const float mApf = mask_at(mFp, r, flag) ? 1.f : 0.f;
        const float mAjf = mask_at(mFj, r, flag) ? 1.f : 0.f;

        float sse = 0.f, apn = 0.f, lsAj = 0.f, lsAc = 0.f;
        unsigned long long key = ~0ull;
#pragma unroll
        for (int q = 0; q < 4; ++q) {
            {   // first half: cols c0+q (all < 511)
                const float d0 = an0[q] - ar0[q];
                sse += d0 * d0;
                apn += frelu(-ap0[q]);
                const float dd = ac0[q] - aj0[q];
                lsAj += frelu(-dd); lsAc += frelu(dd);
                const unsigned long long kk =
                    ((unsigned long long)__float_as_uint(fabsf(dd)) << 32) |
                    (unsigned)(c0 + q);
                key = kk < key ? kk : key;
            }
            {   // second half: cols 256+c0+q (col 511 excluded from diff terms)
                const int col = 256 + c0 + q;
                const float d0 = an1[q] - ar1[q];
                sse += d0 * d0;
                apn += frelu(-ap1[q]);
                if (col < L_COLS - 1) {
                    const float dd = ac1[q] - aj1[q];
                    lsAj += frelu(-dd); lsAc += frelu(dd);
                    const unsigned long long kk =
                        ((unsigned long long)__float_as_uint(fabsf(dd)) << 32) |
                        (unsigned)col;
                    key = kk < key ? kk : key;
                }
            }
        }

#pragma unroll
        for (int off = 32; off; off >>= 1) {
            const unsigned long long ok = __shfl_xor(key, off);
            key = ok < key ? ok : key;
            lsAj += __shfl_xor(lsAj, off);
            lsAc += __shfl_xor(lsAc, off);
            sse  += __shfl_xor(sse, off);
            apn  += __shfl_xor(apn, off);
        }

        const int bcol = (int)(key & 0xffffffffull);       // wave-uniform
        const int qq = bcol & 3;
        const float candJ = (bcol < 256) ? aj0[qq] : aj1[qq];
        const float candP = (bcol < 256) ? ap0[qq] : ap1[qq];
        const int owner = (bcol < 256) ? (bcol >> 2) : ((bcol - 256) >> 2);
        const float bAj = __shfl(candJ, owner);
        const float bAp = __shfl(candP, owner);
        const float eAc = __shfl(ac1[3], 63);
        const float eAj = __shfl(aj1[3], 63);
        const float eAp = __shfl(ap1[3], 63);

        __shared__ float sA[4], sB[4];
        if (lane == 0) {
            sA[wv] = apn
                   + 0.15f * (mApf * frelu(eAp - eAj))
                   + (mAjf * frelu(eAj - eAc))
                   + 5.0f * frelu(1.1f * bAj - bAp)
                   + (mAjf * (frelu(8.f - lsAj) + frelu(8.f - lsAc)));
            sB[wv] = sse;
        }
        __syncthreads();
        if (threadIdx.x == 0)
            part[bid] = make_float2(sA[0] + sA[1] + sA[2] + sA[3],
                                    sB[0] + sB[1] + sB[2] + sB[3]);
    } else {
        // ---------------- masked stats over C-length arrays ------------------
        const int sid = bid - NB_ROW;
        const int flag = detect_flag(mNL);
        double a[10];
#pragma unroll
        for (int t = 0; t < 10; ++t) a[t] = 0.0;
        for (int i = sid * 256 + threadIdx.x; i < C_ROWS; i += NB_ST * 256) {
            const float v = V[i], j = J[i], rr = R[i];
            if (mask_at(mNL, i, flag)) {
                a[0] += 1.0;
                a[1] += (double)v;  a[2] += (double)v * v;
                a[3] += (double)j;  a[4] += (double)j * j;  a[5] += (double)j * v;
                a[6] += (double)rr; a[7] += (double)rr * rr; a[8] += (double)rr * v;
            }
            a[9] += (double)frelu(-rr);
        }
#pragma unroll
        for (int t = 0; t < 10; ++t)
            for (int off = 32; off; off >>= 1) a[t] += __shfl_xor(a[t], off);
        __shared__ double sst[4][10];
        if (lane == 0) {
#pragma unroll
            for (int t = 0; t < 10; ++t) sst[wv][t] = a[t];
        }
        __syncthreads();
        if (threadIdx.x == 0) {
            double* slot = stats + sid * 10;
#pragma unroll
            for (int t = 0; t < 10; ++t)
                slot[t] = sst[0][t] + sst[1][t] + sst[2][t] + sst[3][t];
        }
    }

    // -------------------- tail: last block finishes the reduction ------------
    __shared__ unsigned sIsLast;
    if (threadIdx.x == 0) {
        __threadfence();   // make this block's partial visible device-wide
        const unsigned prev = atomicAdd((unsigned*)((char*)ws + CTR_OFF), 1u);
        sIsLast = (prev == GRID - 1) ? 1u : 0u;
    }
    __syncthreads();
    if (!sIsLast) return;
    __threadfence();       // acquire: all partials now visible

    __shared__ double sm[4], ssum[4], sStat[10];
    double m = 0.0, s = 0.0;
    for (int i = threadIdx.x; i < NB_ROW; i += 256) {
        const float2 v = part[i];
        m += (double)v.x; s += (double)v.y;
    }
#pragma unroll
    for (int off = 32; off; off >>= 1) {
        m += __shfl_xor(m, off);
        s += __shfl_xor(s, off);
    }
    if (lane == 0) { sm[wv] = m; ssum[wv] = s; }
    if (threadIdx.x < 10) {           // 10 threads, 32 independent loads each
        double acc = 0.0;
        for (int sd = 0; sd < NB_ST; ++sd) acc += stats[sd * 10 + threadIdx.x];
        sStat[threadIdx.x] = acc;
    }
    __syncthreads();
    if (threadIdx.x == 0) {
        const double miscSum = sm[0] + sm[1] + sm[2] + sm[3];
        const double sseSum  = ssum[0] + ssum[1] + ssum[2] + ssum[3];
        double total = miscSum + 10.0 * sseSum / (double)N_TOT;
        total += corrterm(sStat[0], sStat[3], sStat[4], sStat[1], sStat[2], sStat[5], 0.7);
        total += corrterm(sStat[0], sStat[6], sStat[7], sStat[1], sStat[2], sStat[8], 0.4);
        total += sStat[9];             // sum(relu(-Rd25))
        double p = 0.0;
        for (int i = 0; i < 8; ++i) {
            p += 10.0 * (double)frelu(-dHaV[i]) + (double)frelu(-dHaJ[i]) + (double)frelu(-dHaT[i]);
            p += (double)frelu(273.15f - ToV[i]) + (double)frelu(273.15f - ToJ[i])
               + (double)frelu(273.15f - ToT[i]);
            p += (double)frelu(-gm[i]);
        }
        total += p;
        out[0] = (float)total;
    }
}

extern "C" void kernel_launch(void* const* d_in, const int* in_sizes, int n_in,
                              void* d_out, int out_size, void* d_ws, size_t ws_size,
                              hipStream_t stream) {
    const float* An  = (const float*)d_in[0];
    const float* Ac  = (const float*)d_in[1];
    const float* Aj  = (const float*)d_in[2];
    const float* Ap  = (const float*)d_in[3];
    const float* Ar  = (const float*)d_in[4];
    const float* V   = (const float*)d_in[5];
    const float* J   = (const float*)d_in[6];
    const float* R   = (const float*)d_in[7];
    const float* dHaV = (const float*)d_in[8];
    const float* dHaJ = (const float*)d_in[9];
    const float* dHaT = (const float*)d_in[10];
    const float* ToV  = (const float*)d_in[11];
    const float* ToJ  = (const float*)d_in[12];
    const float* ToT  = (const float*)d_in[13];
    const float* gmv  = (const float*)d_in[14];
    const void* mNL = d_in[15];
    const void* mFp = d_in[16];
    const void* mFj = d_in[17];

    hipMemsetAsync((char*)d_ws + CTR_OFF, 0, 4, stream);   // zero ticket counter
    fused_kernel<<<GRID, 256, 0, stream>>>(An, Ac, Aj, Ap, Ar, V, J, R,
                                           mNL, mFp, mFj,
                                           dHaV, dHaJ, dHaT, ToV, ToJ, ToT, gmv,
                                           d_ws, (float*)d_out);
}

// Round 9
// 64.877 us; speedup vs baseline: 7.1710x; 7.1710x over previous
//
#include <hip/hip_runtime.h>

typedef float f4 __attribute__((ext_vector_type(4)));

#define C_ROWS 32768
#define L_COLS 512
#define N_TOT  (C_ROWS * (size_t)L_COLS)

#define NB_ROW 8192                // row blocks: 4 waves, 1 row per wave
#define NB_ST  32                  // dedicated stats blocks (tiny)
#define GRID   (NB_ROW + NB_ST)

// ws layout (bytes):
//   [0, 64K)          : NB_ROW float2 — per-row-block partials (misc, sse)
//   [64K, 64K+2560)   : NB_ST * 10 doubles — per-stats-block partials
#define STATS_OFF 65536

__device__ __forceinline__ float frelu(float x) { return x > 0.f ? x : 0.f; }

__device__ __forceinline__ f4 ntload(const float* p) {
    return __builtin_nontemporal_load((const f4*)p);
}

__device__ __forceinline__ bool mask_at(const void* p, int i, int flag) {
    if (flag == 1) return ((const int*)p)[i] != 0;
    if (flag == 2) return ((const float*)p)[i] != 0.f;
    return ((const unsigned char*)p)[i] != 0;
}

// Per-wave mask-dtype detect from first 512 words (2 KB) of mask_nolightresp.
__device__ __forceinline__ int detect_flag(const void* m) {
    const int lane = threadIdx.x & 63;
    const uint4* p = (const uint4*)m;
    const uint4 a = p[lane * 2], b = p[lane * 2 + 1];
    unsigned w[8] = {a.x, a.y, a.z, a.w, b.x, b.y, b.z, b.w};
    int anyMid = 0, anyF = 0;
#pragma unroll
    for (int k = 0; k < 8; ++k) {
        if (w[k] & ~1u) anyMid = 1;
        if (w[k] == 0x3f800000u) anyF = 1;
    }
    const bool hasF   = __ballot(anyF) != 0ull;
    const bool hasMid = __ballot(anyMid) != 0ull;
    return hasF ? 2 : (hasMid ? 0 : 1);
}

// ----------------------------------------------------------------- fused ----
__global__ __launch_bounds__(256) void fused_kernel(const float* __restrict__ An,
                                                    const float* __restrict__ Ac,
                                                    const float* __restrict__ Aj,
                                                    const float* __restrict__ Ap,
                                                    const float* __restrict__ Ar,
                                                    const float* __restrict__ V,
                                                    const float* __restrict__ J,
                                                    const float* __restrict__ R,
                                                    const void* __restrict__ mNL,
                                                    const void* __restrict__ mFp,
                                                    const void* __restrict__ mFj,
                                                    void* ws) {
    const int lane = threadIdx.x & 63;
    const int wv   = threadIdx.x >> 6;
    const int bid  = blockIdx.x;

    if (bid < NB_ROW) {
        // ---------------- row logic: 1 row per wave, all 5 arrays ------------
        const int r = bid * 4 + wv;
        const size_t base = (size_t)r * L_COLS;
        const int c0 = lane * 4;

        const f4 an0 = ntload(An + base + c0);
        const f4 an1 = ntload(An + base + 256 + c0);
        const f4 ar0 = ntload(Ar + base + c0);
        const f4 ar1 = ntload(Ar + base + 256 + c0);
        const f4 ap0 = ntload(Ap + base + c0);
        const f4 ap1 = ntload(Ap + base + 256 + c0);
        const f4 ac0 = ntload(Ac + base + c0);
        const f4 ac1 = ntload(Ac + base + 256 + c0);
        const f4 aj0 = ntload(Aj + base + c0);
        const f4 aj1 = ntload(Aj + base + 256 + c0);

        const int flag = detect_flag(mNL);     // overlaps with big loads
        const float mApf = mask_at(mFp, r, flag) ? 1.f : 0.f;
        const float mAjf = mask_at(mFj, r, flag) ? 1.f : 0.f;

        float sse = 0.f, apn = 0.f, lsAj = 0.f, lsAc = 0.f;
        unsigned long long key = ~0ull;
#pragma unroll
        for (int q = 0; q < 4; ++q) {
            {   // first half: cols c0+q (all < 511)
                const float d0 = an0[q] - ar0[q];
                sse += d0 * d0;
                apn += frelu(-ap0[q]);
                const float dd = ac0[q] - aj0[q];
                lsAj += frelu(-dd); lsAc += frelu(dd);
                const unsigned long long kk =
                    ((unsigned long long)__float_as_uint(fabsf(dd)) << 32) |
                    (unsigned)(c0 + q);
                key = kk < key ? kk : key;
            }
            {   // second half: cols 256+c0+q (col 511 excluded from diff terms)
                const int col = 256 + c0 + q;
                const float d0 = an1[q] - ar1[q];
                sse += d0 * d0;
                apn += frelu(-ap1[q]);
                if (col < L_COLS - 1) {
                    const float dd = ac1[q] - aj1[q];
                    lsAj += frelu(-dd); lsAc += frelu(dd);
                    const unsigned long long kk =
                        ((unsigned long long)__float_as_uint(fabsf(dd)) << 32) |
                        (unsigned)col;
                    key = kk < key ? kk : key;
                }
            }
        }

        // butterfly: all lanes end with wave-reduced values
#pragma unroll
        for (int off = 32; off; off >>= 1) {
            const unsigned long long ok = __shfl_xor(key, off);
            key = ok < key ? ok : key;
            lsAj += __shfl_xor(lsAj, off);
            lsAc += __shfl_xor(lsAc, off);
            sse  += __shfl_xor(sse, off);
            apn  += __shfl_xor(apn, off);
        }

        // argmin values via shfl — no scattered global loads
        const int bcol = (int)(key & 0xffffffffull);       // wave-uniform
        const int qq = bcol & 3;
        const float candJ = (bcol < 256) ? aj0[qq] : aj1[qq];
        const float candP = (bcol < 256) ? ap0[qq] : ap1[qq];
        const int owner = (bcol < 256) ? (bcol >> 2) : ((bcol - 256) >> 2);
        const float bAj = __shfl(candJ, owner);
        const float bAp = __shfl(candP, owner);
        const float eAc = __shfl(ac1[3], 63);
        const float eAj = __shfl(aj1[3], 63);
        const float eAp = __shfl(ap1[3], 63);

        __shared__ float sA[4], sB[4];
        if (lane == 0) {
            sA[wv] = apn
                   + 0.15f * (mApf * frelu(eAp - eAj))
                   + (mAjf * frelu(eAj - eAc))
                   + 5.0f * frelu(1.1f * bAj - bAp)
                   + (mAjf * (frelu(8.f - lsAj) + frelu(8.f - lsAc)));
            sB[wv] = sse;
        }
        __syncthreads();
        if (threadIdx.x == 0) {
            float2* part = (float2*)ws;
            part[bid] = make_float2(sA[0] + sA[1] + sA[2] + sA[3],
                                    sB[0] + sB[1] + sB[2] + sB[3]);
        }
    } else {
        // ---------------- masked stats over C-length arrays ------------------
        const int sid = bid - NB_ROW;
        const int flag = detect_flag(mNL);
        double a[10];
#pragma unroll
        for (int t = 0; t < 10; ++t) a[t] = 0.0;
        for (int i = sid * 256 + threadIdx.x; i < C_ROWS; i += NB_ST * 256) {
            const float v = V[i], j = J[i], rr = R[i];
            if (mask_at(mNL, i, flag)) {
                a[0] += 1.0;
                a[1] += (double)v;  a[2] += (double)v * v;
                a[3] += (double)j;  a[4] += (double)j * j;  a[5] += (double)j * v;
                a[6] += (double)rr; a[7] += (double)rr * rr; a[8] += (double)rr * v;
            }
            a[9] += (double)frelu(-rr);
        }
#pragma unroll
        for (int t = 0; t < 10; ++t)
            for (int off = 32; off; off >>= 1) a[t] += __shfl_xor(a[t], off);
        __shared__ double sst[4][10];
        if (lane == 0) {
#pragma unroll
            for (int t = 0; t < 10; ++t) sst[wv][t] = a[t];
        }
        __syncthreads();
        if (threadIdx.x == 0) {
            double* slot = (double*)((char*)ws + STATS_OFF) + sid * 10;
#pragma unroll
            for (int t = 0; t < 10; ++t)
                slot[t] = sst[0][t] + sst[1][t] + sst[2][t] + sst[3][t];
        }
    }
}

// ----------------------------------------------------------------- final ----
__device__ double corrterm(double n, double Sx, double Sxx, double Sy, double Syy,
                           double Sxy, double target) {
    const double mx = Sx / n, my = Sy / n;
    const double cov = Sxy - n * mx * my;
    const double vx  = Sxx - n * mx * mx;
    const double vy  = Syy - n * my * my;
    double cost = cov / (sqrt(vx) * sqrt(vy));
    if (isnan(cost)) cost = 0.0;
    const double cmin = cost < target ? cost : target;
    return target - cmin;
}

__global__ __launch_bounds__(256) void final_kernel(const float* __restrict__ dHaV,
                                                    const float* __restrict__ dHaJ,
                                                    const float* __restrict__ dHaT,
                                                    const float* __restrict__ ToV,
                                                    const float* __restrict__ ToJ,
                                                    const float* __restrict__ ToT,
                                                    const float* __restrict__ gm,
                                                    void* ws, float* out) {
    const int lane = threadIdx.x & 63;
    const int wv   = threadIdx.x >> 6;
    __shared__ double sm[4], ss[4], sStat[10];

    double m = 0.0, s = 0.0;
    const float2* part = (const float2*)ws;
    for (int i = threadIdx.x; i < NB_ROW; i += 256) {
        const float2 v = part[i];
        m += (double)v.x; s += (double)v.y;
    }
#pragma unroll
    for (int off = 32; off; off >>= 1) {
        m += __shfl_xor(m, off);
        s += __shfl_xor(s, off);
    }
    if (lane == 0) { sm[wv] = m; ss[wv] = s; }
    if (threadIdx.x < 10) {           // 10 threads, 32 independent loads each
        const double* slots = (const double*)((const char*)ws + STATS_OFF);
        double acc = 0.0;
        for (int sd = 0; sd < NB_ST; ++sd) acc += slots[sd * 10 + threadIdx.x];
        sStat[threadIdx.x] = acc;
    }
    __syncthreads();
    if (threadIdx.x == 0) {
        const double miscSum = sm[0] + sm[1] + sm[2] + sm[3];
        const double sseSum  = ss[0] + ss[1] + ss[2] + ss[3];
        double total = miscSum + 10.0 * sseSum / (double)N_TOT;
        total += corrterm(sStat[0], sStat[3], sStat[4], sStat[1], sStat[2], sStat[5], 0.7);
        total += corrterm(sStat[0], sStat[6], sStat[7], sStat[1], sStat[2], sStat[8], 0.4);
        total += sStat[9];             // sum(relu(-Rd25))
        double p = 0.0;
        for (int i = 0; i < 8; ++i) {
            p += 10.0 * (double)frelu(-dHaV[i]) + (double)frelu(-dHaJ[i]) + (double)frelu(-dHaT[i]);
            p += (double)frelu(273.15f - ToV[i]) + (double)frelu(273.15f - ToJ[i])
               + (double)frelu(273.15f - ToT[i]);
            p += (double)frelu(-gm[i]);
        }
        total += p;
        out[0] = (float)total;
    }
}

extern "C" void kernel_launch(void* const* d_in, const int* in_sizes, int n_in,
                              void* d_out, int out_size, void* d_ws, size_t ws_size,
                              hipStream_t stream) {
    const float* An  = (const float*)d_in[0];
    const float* Ac  = (const float*)d_in[1];
    const float* Aj  = (const float*)d_in[2];
    const float* Ap  = (const float*)d_in[3];
    const float* Ar  = (const float*)d_in[4];
    const float* V   = (const float*)d_in[5];
    const float* J   = (const float*)d_in[6];
    const float* R   = (const float*)d_in[7];
    const float* dHaV = (const float*)d_in[8];
    const float* dHaJ = (const float*)d_in[9];
    const float* dHaT = (const float*)d_in[10];
    const float* ToV  = (const float*)d_in[11];
    const float* ToJ  = (const float*)d_in[12];
    const float* ToT  = (const float*)d_in[13];
    const float* gmv  = (const float*)d_in[14];
    const void* mNL = d_in[15];
    const void* mFp = d_in[16];
    const void* mFj = d_in[17];

    fused_kernel<<<GRID, 256, 0, stream>>>(An, Ac, Aj, Ap, Ar, V, J, R,
                                           mNL, mFp, mFj, d_ws);
    final_kernel<<<1, 256, 0, stream>>>(dHaV, dHaJ, dHaT, ToV, ToJ, ToT, gmv, d_ws,
                                        (float*)d_out);
}